// Round 5
// baseline (160.227 us; speedup 1.0000x reference)
//
#include <hip/hip_runtime.h>
#include <hip/hip_fp16.h>
#include <hip/hip_cooperative_groups.h>
#include <float.h>

namespace cg = cooperative_groups;

#define N_CB  15
#define MAXB  1024  // desired coop grid: 4 blocks/CU on 256 CUs
#define NTHR  256

// ws float layout:
//   coop path:     [0..MAXB) per-block mins, [MAXB..2*MAXB) per-block maxs
//   fallback path: [4096..4608) mins, [4608..5120) maxs, [5120..5135) codebook
// Every slot read is written earlier in the same call — poison-safe, no init.

__device__ __forceinline__ float q4_lookup(float xv, float mn, float range,
                                           const float* cb) {
    // EXACT f32 mirror of the reference: t = (x-mn)/(mx-mn) * 2.0f + (-1.0f).
    // Real division (no reciprocal); *2.0f is exponent-exact so fma
    // contraction cannot change the rounded result.
    float t = (xv - mn) / range * 2.0f - 1.0f;
    float best = fabsf(t - cb[0]);
    float val  = cb[0];
    #pragma unroll
    for (int j = 1; j < N_CB; j++) {
        float d = fabsf(t - cb[j]);
        if (d < best) { best = d; val = cb[j]; }  // strict <: first-index tie-break == jnp.argmin
    }
    return val;
}

__device__ __forceinline__ void q4_load_cb(const void* __restrict__ cb_raw, float* cb) {
    // Codebook dtype sniff: codebook[0] is exactly -1.0. f32 layout iff the
    // first 32-bit word == -1.0f (0xBF800000); raw fp16 otherwise.
    const float* cf = (const float*)cb_raw;
    if (cf[0] == -1.0f) {
        #pragma unroll
        for (int j = 0; j < N_CB; j++) cb[j] = cf[j];
    } else {
        const __half* ch = (const __half*)cb_raw;
        #pragma unroll
        for (int j = 0; j < N_CB; j++) cb[j] = __half2float(ch[j]);
    }
}

// ---------------------------------------------------------------------------
// Fused cooperative kernel. NO register/LDS data holding across the sync —
// round-4 showed the allocator spills it (VGPR 48, 80 µs dispatch). Instead:
// phase 1 reads x from HBM (min/max), grid.sync, phase 2 re-reads x from
// L3 (fully resident: 33.5 MB << 256 MiB) overlapped with the HBM write.
// ---------------------------------------------------------------------------
__global__ __launch_bounds__(NTHR) void q4_fused_kernel(
        const float4* __restrict__ x4, float4* __restrict__ out4, int n4,
        const float* __restrict__ x, float* __restrict__ out, int n,
        const void* __restrict__ cb_raw, float* __restrict__ ws) {
    cg::grid_group grid = cg::this_grid();
    const int g  = blockIdx.x * NTHR + threadIdx.x;
    const int G  = gridDim.x * NTHR;
    const int nb = gridDim.x;

    // ---- Phase 1: grid-stride min/max over x ----
    float mn = FLT_MAX, mx = -FLT_MAX;
    for (int i = g; i < n4; i += G) {
        float4 t = x4[i];
        mn = fminf(mn, fminf(fminf(t.x, t.y), fminf(t.z, t.w)));
        mx = fmaxf(mx, fmaxf(fmaxf(t.x, t.y), fmaxf(t.z, t.w)));
    }
    for (int i = n4 * 4 + g; i < n; i += G) {     // scalar tail (n % 4)
        float t = x[i];
        mn = fminf(mn, t);
        mx = fmaxf(mx, t);
    }

    // ---- Block reduce -> per-block partial ----
    #pragma unroll
    for (int off = 32; off; off >>= 1) {
        mn = fminf(mn, __shfl_down(mn, off));
        mx = fmaxf(mx, __shfl_down(mx, off));
    }
    __shared__ float smn[4], smx[4];
    __shared__ float sfin[2];
    const int wave = threadIdx.x >> 6, lane = threadIdx.x & 63;
    if (lane == 0) { smn[wave] = mn; smx[wave] = mx; }
    __syncthreads();
    if (threadIdx.x == 0) {
        ws[blockIdx.x]        = fminf(fminf(smn[0], smn[1]), fminf(smn[2], smn[3]));
        ws[MAXB + blockIdx.x] = fmaxf(fmaxf(smx[0], smx[1]), fmaxf(smx[2], smx[3]));
    }

    // ---- Grid-wide barrier (publishes partials device-wide) ----
    grid.sync();

    // ---- Every block self-reduces the nb partials (L2-hot) ----
    mn = FLT_MAX; mx = -FLT_MAX;
    for (int j = threadIdx.x; j < nb; j += NTHR) {
        mn = fminf(mn, ws[j]);
        mx = fmaxf(mx, ws[MAXB + j]);
    }
    #pragma unroll
    for (int off = 32; off; off >>= 1) {
        mn = fminf(mn, __shfl_down(mn, off));
        mx = fmaxf(mx, __shfl_down(mx, off));
    }
    if (lane == 0) { smn[wave] = mn; smx[wave] = mx; }
    __syncthreads();
    if (threadIdx.x == 0) {
        sfin[0] = fminf(fminf(smn[0], smn[1]), fminf(smn[2], smn[3]));
        sfin[1] = fmaxf(fmaxf(smx[0], smx[1]), fmaxf(smx[2], smx[3]));
    }

    // Codebook (wave-uniform scalar loads), then pick up block-final min/max.
    float cb[N_CB];
    q4_load_cb(cb_raw, cb);
    __syncthreads();
    const float fmn   = sfin[0];
    const float range = sfin[1] - fmn;

    // ---- Phase 2: re-read x (L3-hot), transform, write ----
    for (int i = g; i < n4; i += G) {
        float4 t = x4[i];
        float4 o;
        o.x = q4_lookup(t.x, fmn, range, cb);
        o.y = q4_lookup(t.y, fmn, range, cb);
        o.z = q4_lookup(t.z, fmn, range, cb);
        o.w = q4_lookup(t.w, fmn, range, cb);
        out4[i] = o;
    }
    for (int i = n4 * 4 + g; i < n; i += G) {     // scalar tail
        out[i] = q4_lookup(x[i], fmn, range, cb);
    }
}

// ---------------------------------------------------------------------------
// Fallback path (round-2 structure, known-good 97.3 µs).
// ---------------------------------------------------------------------------
#define FB_OFF    4096
#define FB_BLOCKS 512

__global__ __launch_bounds__(NTHR) void q4_partials_kernel(
        const float4* __restrict__ x4, int n4,
        const float* __restrict__ x, int n,
        float* __restrict__ ws, const void* __restrict__ cb_raw) {
    if (blockIdx.x == 0 && threadIdx.x == 0) {
        float cb[N_CB];
        q4_load_cb(cb_raw, cb);
        for (int j = 0; j < N_CB; j++) ws[FB_OFF + 1024 + j] = cb[j];
    }
    float mn = FLT_MAX, mx = -FLT_MAX;
    int tid = blockIdx.x * NTHR + threadIdx.x;
    int stride = gridDim.x * NTHR;
    for (int i = tid; i < n4; i += stride) {
        float4 v = x4[i];
        mn = fminf(mn, fminf(fminf(v.x, v.y), fminf(v.z, v.w)));
        mx = fmaxf(mx, fmaxf(fmaxf(v.x, v.y), fmaxf(v.z, v.w)));
    }
    if (blockIdx.x == 0) {
        for (int i = n4 * 4 + threadIdx.x; i < n; i += NTHR) {
            float v = x[i];
            mn = fminf(mn, v);
            mx = fmaxf(mx, v);
        }
    }
    #pragma unroll
    for (int off = 32; off; off >>= 1) {
        mn = fminf(mn, __shfl_down(mn, off));
        mx = fmaxf(mx, __shfl_down(mx, off));
    }
    __shared__ float smn[4], smx[4];
    int wave = threadIdx.x >> 6, lane = threadIdx.x & 63;
    if (lane == 0) { smn[wave] = mn; smx[wave] = mx; }
    __syncthreads();
    if (threadIdx.x == 0) {
        ws[FB_OFF + blockIdx.x]       = fminf(fminf(smn[0], smn[1]), fminf(smn[2], smn[3]));
        ws[FB_OFF + 512 + blockIdx.x] = fmaxf(fmaxf(smx[0], smx[1]), fmaxf(smx[2], smx[3]));
    }
}

__global__ __launch_bounds__(NTHR) void q4_transform_kernel(
        const float4* __restrict__ x4, float4* __restrict__ out4, int n4,
        const float* __restrict__ x, float* __restrict__ out, int n,
        const float* __restrict__ ws) {
    int base = blockIdx.x * (NTHR * 2) + threadIdx.x;
    bool h0 = base < n4, h1 = (base + NTHR) < n4;
    float4 v0, v1;
    if (h0) v0 = x4[base];
    if (h1) v1 = x4[base + NTHR];

    float mn = fminf(ws[FB_OFF + threadIdx.x],       ws[FB_OFF + threadIdx.x + 256]);
    float mx = fmaxf(ws[FB_OFF + 512 + threadIdx.x], ws[FB_OFF + 768 + threadIdx.x]);
    #pragma unroll
    for (int off = 32; off; off >>= 1) {
        mn = fminf(mn, __shfl_down(mn, off));
        mx = fmaxf(mx, __shfl_down(mx, off));
    }
    __shared__ float sred[8];
    __shared__ float sfin[2];
    int wave = threadIdx.x >> 6, lane = threadIdx.x & 63;
    if (lane == 0) { sred[wave] = mn; sred[4 + wave] = mx; }
    __syncthreads();
    if (threadIdx.x == 0) {
        sfin[0] = fminf(fminf(sred[0], sred[1]), fminf(sred[2], sred[3]));
        sfin[1] = fmaxf(fmaxf(sred[4], sred[5]), fmaxf(sred[6], sred[7]));
    }
    float cb[N_CB];
    #pragma unroll
    for (int j = 0; j < N_CB; j++) cb[j] = ws[FB_OFF + 1024 + j];
    __syncthreads();
    float fmn = sfin[0];
    float range = sfin[1] - fmn;

    if (h0) {
        float4 o;
        o.x = q4_lookup(v0.x, fmn, range, cb);
        o.y = q4_lookup(v0.y, fmn, range, cb);
        o.z = q4_lookup(v0.z, fmn, range, cb);
        o.w = q4_lookup(v0.w, fmn, range, cb);
        out4[base] = o;
    }
    if (h1) {
        float4 o;
        o.x = q4_lookup(v1.x, fmn, range, cb);
        o.y = q4_lookup(v1.y, fmn, range, cb);
        o.z = q4_lookup(v1.z, fmn, range, cb);
        o.w = q4_lookup(v1.w, fmn, range, cb);
        out4[base + NTHR] = o;
    }
    if (blockIdx.x == 0) {
        for (int k = n4 * 4 + threadIdx.x; k < n; k += NTHR) {
            out[k] = q4_lookup(x[k], fmn, range, cb);
        }
    }
}

extern "C" void kernel_launch(void* const* d_in, const int* in_sizes, int n_in,
                              void* d_out, int out_size, void* d_ws, size_t ws_size,
                              hipStream_t stream) {
    const float* x = (const float*)d_in[0];
    const void* cb = d_in[1];
    float* out = (float*)d_out;   // fp16 reference output -> f32 buffer per harness
    int n = in_sizes[0];          // 2048*4096
    int n4 = n >> 2;
    float* ws = (float*)d_ws;

    const float4* x4   = (const float4*)x;
    float4*       out4 = (float4*)out;

    // Size the cooperative grid to actual co-residency (capture-safe query).
    int blocksPerCU = 0;
    hipError_t qerr = hipOccupancyMaxActiveBlocksPerMultiprocessor(
        &blocksPerCU, q4_fused_kernel, NTHR, 0);
    int grid = 0;
    if (qerr == hipSuccess && blocksPerCU > 0) {
        grid = blocksPerCU * 256;           // 256 CUs
        if (grid > MAXB) grid = MAXB;
    }

    hipError_t lerr = hipErrorUnknown;
    if (grid > 0) {
        void* args[] = { (void*)&x4, (void*)&out4, (void*)&n4,
                         (void*)&x,  (void*)&out,  (void*)&n,
                         (void*)&cb, (void*)&ws };
        lerr = hipLaunchCooperativeKernel(q4_fused_kernel,
                                          dim3(grid), dim3(NTHR), args, 0, stream);
    }
    if (lerr != hipSuccess) {
        // Fallback: known-good two-kernel path.
        q4_partials_kernel<<<FB_BLOCKS, NTHR, 0, stream>>>(x4, n4, x, n, ws, cb);
        int bblocks = (n4 + NTHR * 2 - 1) / (NTHR * 2);
        q4_transform_kernel<<<bblocks, NTHR, 0, stream>>>(x4, out4, n4, x, out, n, ws);
    }
}

// Round 7
// 98.551 us; speedup vs baseline: 1.6258x; 1.6258x over previous
//
#include <hip/hip_runtime.h>
#include <hip/hip_fp16.h>
#include <float.h>

#define N_CB  15
#define NTHR  256
#define ABLK  512   // pass-A blocks (2/CU) — HBM-read-bound
#define BVPT  4     // float4s per thread in pass B

// Native clang vector for nontemporal builtin (HIP float4 class is rejected).
typedef float nfloat4 __attribute__((ext_vector_type(4)));

// ws float layout: [0..511] per-block mins, [512..1023] per-block maxs,
// [1024..1038] codebook as f32. Every slot read is written earlier in the
// same call — poison-safe, no init kernel.
//
// NOTE: cooperative/fused single-kernel path was tried (rounds 3-5) and is
// ~7x SLOWER than two plain launches on this stack (80 µs vs 12 µs for the
// same traffic, independent of register pressure) — grid.sync coherence
// cost. Two-kernel structure is the measured winner.

__device__ __forceinline__ void q4_load_cb(const void* __restrict__ cb_raw, float* cb) {
    // Codebook dtype sniff: codebook[0] is exactly -1.0. f32 layout iff the
    // first 32-bit word == -1.0f (0xBF800000); raw fp16 otherwise.
    const float* cf = (const float*)cb_raw;
    if (cf[0] == -1.0f) {
        #pragma unroll
        for (int j = 0; j < N_CB; j++) cb[j] = cf[j];
    } else {
        const __half* ch = (const __half*)cb_raw;
        #pragma unroll
        for (int j = 0; j < N_CB; j++) cb[j] = __half2float(ch[j]);
    }
}

__device__ __forceinline__ float q4_lookup(float xv, float mn, float range,
                                           const float* cb) {
    // EXACT f32 mirror of the reference: t = (x-mn)/(mx-mn) * 2.0f + (-1.0f).
    // Real division (no reciprocal); *2.0f is exponent-exact so fma
    // contraction cannot change the rounded result.
    float t = (xv - mn) / range * 2.0f - 1.0f;
    // Nearest-codebook scan, 4 VALU/entry: sub, cmp(abs-mod), min(abs-mod),
    // cndmask. Semantics identical to the reference |t-c| argmin with strict-<
    // (first-index tie-break == jnp.argmin): lt uses the PRE-update dmin.
    float s0   = t - cb[0];
    float dmin = fabsf(s0);
    float val  = cb[0];
    #pragma unroll
    for (int j = 1; j < N_CB; j++) {
        float s  = t - cb[j];
        bool  lt = fabsf(s) < dmin;
        dmin = fminf(fabsf(s), dmin);
        val  = lt ? cb[j] : val;
    }
    return val;
}

// ---------------------------------------------------------------------------
// Pass A: grid-stride min/max -> 512 per-block partials; also stages codebook.
// ---------------------------------------------------------------------------
__global__ __launch_bounds__(NTHR) void q4_partials_kernel(
        const float4* __restrict__ x4, int n4,
        const float* __restrict__ x, int n,
        float* __restrict__ ws, const void* __restrict__ cb_raw) {
    if (blockIdx.x == 0 && threadIdx.x == 0) {
        float cb[N_CB];
        q4_load_cb(cb_raw, cb);
        #pragma unroll
        for (int j = 0; j < N_CB; j++) ws[1024 + j] = cb[j];
    }
    float mn = FLT_MAX, mx = -FLT_MAX;
    int tid = blockIdx.x * NTHR + threadIdx.x;
    int stride = gridDim.x * NTHR;
    for (int i = tid; i < n4; i += stride) {
        float4 v = x4[i];
        mn = fminf(fminf(mn, fminf(v.x, v.y)), fminf(v.z, v.w));
        mx = fmaxf(fmaxf(mx, fmaxf(v.x, v.y)), fmaxf(v.z, v.w));
    }
    if (blockIdx.x == 0) {           // scalar tail (n % 4) — no-op here
        for (int i = n4 * 4 + threadIdx.x; i < n; i += NTHR) {
            float v = x[i];
            mn = fminf(mn, v);
            mx = fmaxf(mx, v);
        }
    }
    #pragma unroll
    for (int off = 32; off; off >>= 1) {
        mn = fminf(mn, __shfl_down(mn, off));
        mx = fmaxf(mx, __shfl_down(mx, off));
    }
    __shared__ float smn[4], smx[4];
    int wave = threadIdx.x >> 6, lane = threadIdx.x & 63;
    if (lane == 0) { smn[wave] = mn; smx[wave] = mx; }
    __syncthreads();
    if (threadIdx.x == 0) {
        ws[blockIdx.x]       = fminf(fminf(smn[0], smn[1]), fminf(smn[2], smn[3]));
        ws[512 + blockIdx.x] = fmaxf(fmaxf(smx[0], smx[1]), fmaxf(smx[2], smx[3]));
    }
}

// ---------------------------------------------------------------------------
// Pass B: per-block reduce of the 512 partials (L2-hot, hidden under the x
// loads issued first), then transform 4 float4/thread, non-temporal stores.
// ---------------------------------------------------------------------------
__global__ __launch_bounds__(NTHR) void q4_transform_kernel(
        const float4* __restrict__ x4, float4* __restrict__ out4, int n4,
        const float* __restrict__ x, float* __restrict__ out, int n,
        const float* __restrict__ ws) {
    // Issue the x loads FIRST so the partial-reduce latency hides under them.
    int base = blockIdx.x * (NTHR * BVPT) + threadIdx.x;
    float4 v[BVPT];
    bool   h[BVPT];
    #pragma unroll
    for (int j = 0; j < BVPT; j++) {
        int i = base + j * NTHR;
        h[j] = (i < n4);
        if (h[j]) v[j] = x4[i];
    }

    // Reduce the 512 partials.
    float mn = fminf(ws[threadIdx.x],       ws[threadIdx.x + 256]);
    float mx = fmaxf(ws[512 + threadIdx.x], ws[768 + threadIdx.x]);
    #pragma unroll
    for (int off = 32; off; off >>= 1) {
        mn = fminf(mn, __shfl_down(mn, off));
        mx = fmaxf(mx, __shfl_down(mx, off));
    }
    __shared__ float sred[8];
    __shared__ float sfin[2];
    int wave = threadIdx.x >> 6, lane = threadIdx.x & 63;
    if (lane == 0) { sred[wave] = mn; sred[4 + wave] = mx; }
    __syncthreads();
    if (threadIdx.x == 0) {
        sfin[0] = fminf(fminf(sred[0], sred[1]), fminf(sred[2], sred[3]));
        sfin[1] = fmaxf(fmaxf(sred[4], sred[5]), fmaxf(sred[6], sred[7]));
    }
    float cb[N_CB];
    #pragma unroll
    for (int j = 0; j < N_CB; j++) cb[j] = ws[1024 + j];
    __syncthreads();
    const float fmn   = sfin[0];
    const float range = sfin[1] - fmn;

    #pragma unroll
    for (int j = 0; j < BVPT; j++) {
        if (h[j]) {
            nfloat4 o;
            o.x = q4_lookup(v[j].x, fmn, range, cb);
            o.y = q4_lookup(v[j].y, fmn, range, cb);
            o.z = q4_lookup(v[j].z, fmn, range, cb);
            o.w = q4_lookup(v[j].w, fmn, range, cb);
            // Streaming store (nt): output is never re-read; keep L2 for x.
            __builtin_nontemporal_store(o, (nfloat4*)&out4[base + j * NTHR]);
        }
    }
    if (blockIdx.x == 0) {           // scalar tail (n % 4) — no-op here
        for (int k = n4 * 4 + threadIdx.x; k < n; k += NTHR) {
            out[k] = q4_lookup(x[k], fmn, range, cb);
        }
    }
}

extern "C" void kernel_launch(void* const* d_in, const int* in_sizes, int n_in,
                              void* d_out, int out_size, void* d_ws, size_t ws_size,
                              hipStream_t stream) {
    const float* x = (const float*)d_in[0];
    const void* cb = d_in[1];
    float* out = (float*)d_out;   // fp16 reference output -> f32 buffer per harness
    int n = in_sizes[0];          // 2048*4096
    int n4 = n >> 2;
    float* ws = (float*)d_ws;

    const float4* x4   = (const float4*)x;
    float4*       out4 = (float4*)out;

    q4_partials_kernel<<<ABLK, NTHR, 0, stream>>>(x4, n4, x, n, ws, cb);

    int bblocks = (n4 + NTHR * BVPT - 1) / (NTHR * BVPT);
    q4_transform_kernel<<<bblocks, NTHR, 0, stream>>>(x4, out4, n4, x, out, n, ws);
}